// Round 3
// baseline (242.538 us; speedup 1.0000x reference)
//
#include <hip/hip_runtime.h>
#include <stdint.h>

#define S_ 8
#define N_ 4096
#define I_ 256
#define L_ 512
#define M_ 256
#define D_ 768   // I + L
#define NT32 24  // 768/32 K-tiles

typedef __bf16 bf16x8 __attribute__((ext_vector_type(8)));
typedef float f32x4 __attribute__((ext_vector_type(4)));
typedef unsigned short ushort_t;

__device__ __forceinline__ unsigned short f2bf(float f) {
  union { float f; uint32_t u; } c; c.f = f;
  uint32_t u = c.u;
  uint32_t r = u + 0x7FFFu + ((u >> 16) & 1u);
  return (unsigned short)(r >> 16);
}

__device__ __forceinline__ float fsigmoid(float x) {
  return 1.0f / (1.0f + __expf(-x));
}
__device__ __forceinline__ float ftanh(float x) {
  float ax = fabsf(x);
  float e = __expf(-2.0f * ax);
  float t = (1.0f - e) / (1.0f + e);
  return copysignf(t, x);
}

#define GLD16(gsrc, ldst)                                                                  \
  __builtin_amdgcn_global_load_lds(                                                        \
      (const __attribute__((address_space(1))) uint32_t*)(uintptr_t)(gsrc),                \
      (__attribute__((address_space(3))) uint32_t*)(uintptr_t)(ldst), 16, 0, 0)

// parity-aware chunk swizzle for BK=32 (4 chunks/row): slot-sharers alternate row parity
#define S4(rr) ((((rr) ^ ((rr) >> 2))) & 3)

// ---------------- prep kernels (no integer division) ----------------

// y selects tensor: 0..3 = Wi/Wf/Wg/Wo -> w4[g], 4 = Wy -> wyb. Flat f32->bf16 copy.
__global__ __launch_bounds__(256) void cast5_kernel(
    const float* __restrict__ Wi, const float* __restrict__ Wf,
    const float* __restrict__ Wg, const float* __restrict__ Wo,
    const float* __restrict__ Wy, ushort_t* __restrict__ w4,
    ushort_t* __restrict__ wyb) {
  const int y = blockIdx.y;
  const int GW = S_ * L_ * D_ / 4;   // 786432 float4 chunks per gate weight
  const float* src;
  ushort_t* dst;
  int n4;
  if (y < 4) {
    src = (y == 0) ? Wi : (y == 1) ? Wf : (y == 2) ? Wg : Wo;
    dst = w4 + (size_t)y * S_ * L_ * D_;
    n4 = GW;
  } else {
    src = Wy; dst = wyb; n4 = S_ * M_ * L_ / 4;
  }
  int t = blockIdx.x * 256 + threadIdx.x;
  int stride = gridDim.x * 256;
  for (; t < n4; t += stride) {
    float4 v = ((const float4*)src)[t];
    ushort4 o;
    o.x = f2bf(v.x); o.y = f2bf(v.y); o.z = f2bf(v.z); o.w = f2bf(v.w);
    ((ushort4*)dst)[t] = o;
  }
}

// xh[s][n][0:256] = mod[n][s*256+:], xh[s][n][256:768] = h0[n][s*512+:]
// y=0: x-part (64 float4-chunks/row), y=1: h-part (128 chunks/row). Pow2 index math only.
__global__ __launch_bounds__(256) void build_xh_kernel(const float* __restrict__ mod,
                                                       const float* __restrict__ h0,
                                                       ushort_t* __restrict__ xh) {
  const int y = blockIdx.y;
  int t = blockIdx.x * 256 + threadIdx.x;
  int stride = gridDim.x * 256;
  if (y == 0) {
    const int total = S_ * N_ * (I_ / 4);          // r = t>>6, c = t&63
    for (; t < total; t += stride) {
      int r = t >> 6, c = t & 63;
      int s = r >> 12, n = r & (N_ - 1);
      float4 v = *(const float4*)(mod + (size_t)n * (S_ * I_) + s * I_ + c * 4);
      ushort4 o;
      o.x = f2bf(v.x); o.y = f2bf(v.y); o.z = f2bf(v.z); o.w = f2bf(v.w);
      *(ushort4*)(xh + (size_t)r * D_ + c * 4) = o;
    }
  } else {
    const int total = S_ * N_ * (L_ / 4);          // r = t>>7, c = t&127
    for (; t < total; t += stride) {
      int r = t >> 7, c = t & 127;
      int s = r >> 12, n = r & (N_ - 1);
      float4 v = *(const float4*)(h0 + (size_t)n * (S_ * L_) + s * L_ + c * 4);
      ushort4 o;
      o.x = f2bf(v.x); o.y = f2bf(v.y); o.z = f2bf(v.z); o.w = f2bf(v.w);
      *(ushort4*)(xh + (size_t)r * D_ + I_ + c * 4) = o;
    }
  }
}

// ---------------- gates: 256n x (4g x 64l) tile, BK=32, 32 KB LDS, 4 blocks/CU ----------------
// 512 threads (8 waves, wm=w>>1 in 0..3 -> 64 n-rows, wl=w&1 -> 32 l-cols, all 4 gates).
// Lane-local cell math: acc[rt][g*2+ct] holds all four gates for the same (n,l).
__global__ __launch_bounds__(512) void gates_kernel(
    const ushort_t* __restrict__ xh,   // [S][N][D] bf16
    const ushort_t* __restrict__ w4,   // [4][S][L][D] bf16
    const float* __restrict__ bi, const float* __restrict__ bff,
    const float* __restrict__ bg, const float* __restrict__ bo,
    const float* __restrict__ c0,      // [N][S*L] f32
    ushort_t* __restrict__ hout)       // [S][N][L] bf16
{
  // A: chunks [0,1024) = 256 rows x 4 chunks; B: chunks [1024,2048). 32 KB total.
  __shared__ __align__(16) ushort_t smem[16384];
  const int tid = threadIdx.x;
  const int lane = tid & 63;
  const int ln15 = lane & 15;
  const int ln4 = lane >> 4;
  const int w = tid >> 6;
  const int wm = w >> 1;
  const int wl = w & 1;

  // stream-per-XCD swizzle: 1024 blocks, all resident (1 generation)
  const int bid = blockIdx.x;
  const int s = bid & 7;
  const int r = bid >> 3;            // 0..127
  const int n0 = (r >> 3) << 8;      // 16 n-blocks of 256
  const int l0 = (r & 7) << 6;       // 8 l-blocks of 64

  const size_t xh_base = (size_t)(s * N_ + n0) * D_;

  f32x4 acc[4][8];
  #pragma unroll
  for (int i = 0; i < 4; ++i)
    #pragma unroll
    for (int j = 0; j < 8; ++j) {
      f32x4 z = {0.f, 0.f, 0.f, 0.f};
      acc[i][j] = z;
    }

  for (int t = 0; t < NT32; ++t) {
    const int k0 = t << 5;
    // stage A (2 rounds of 8 KB) — LDS slot (rr,c) holds global chunk c ^ S4(rr)
    #pragma unroll
    for (int i = 0; i < 2; ++i) {
      int chunk = i * 512 + tid;
      int rr = chunk >> 2, c = chunk & 3;
      const ushort_t* src = xh + xh_base + (size_t)rr * D_ + k0 + ((c ^ S4(rr)) << 3);
      GLD16(src, &smem[(i * 512 + (w << 6)) * 8]);
    }
    // stage B (2 rounds) — row rB = g*64 + l
    #pragma unroll
    for (int i = 0; i < 2; ++i) {
      int chunk = i * 512 + tid;
      int rB = chunk >> 2, c = chunk & 3;
      int g = rB >> 6, ll = rB & 63;
      const ushort_t* src = w4 + ((size_t)((g * S_ + s) * L_) + l0 + ll) * D_ + k0 +
                            ((c ^ S4(rB)) << 3);
      GLD16(src, &smem[(1024 + i * 512 + (w << 6)) * 8]);
    }
    __syncthreads();

    bf16x8 a[4];
    #pragma unroll
    for (int rt = 0; rt < 4; ++rt) {
      int rr = (wm << 6) + (rt << 4) + ln15;
      a[rt] = *(const bf16x8*)&smem[((rr << 2) + (ln4 ^ S4(rr))) * 8];
    }
    bf16x8 b[8];
    #pragma unroll
    for (int g = 0; g < 4; ++g)
      #pragma unroll
      for (int ct = 0; ct < 2; ++ct) {
        int rB = (g << 6) + (wl << 5) + (ct << 4) + ln15;
        b[(g << 1) + ct] = *(const bf16x8*)&smem[(1024 + (rB << 2) + (ln4 ^ S4(rB))) * 8];
      }
    #pragma unroll
    for (int rt = 0; rt < 4; ++rt)
      #pragma unroll
      for (int cj = 0; cj < 8; ++cj)
        acc[rt][cj] = __builtin_amdgcn_mfma_f32_16x16x32_bf16(a[rt], b[cj], acc[rt][cj], 0, 0, 0);
    __syncthreads();
  }

  // Epilogue: D frag layout col = lane&15, row = (lane>>4)*4 + j
  #pragma unroll
  for (int ct = 0; ct < 2; ++ct) {
    const int l = l0 + (wl << 5) + (ct << 4) + ln15;
    const float vbi = bi[s * L_ + l];
    const float vbf = bff[s * L_ + l];
    const float vbg = bg[s * L_ + l];
    const float vbo = bo[s * L_ + l];
    #pragma unroll
    for (int rt = 0; rt < 4; ++rt) {
      #pragma unroll
      for (int j = 0; j < 4; ++j) {
        const int n = n0 + (wm << 6) + (rt << 4) + (ln4 << 2) + j;
        const float c0v = c0[(size_t)n * (S_ * L_) + s * L_ + l];
        const float iv = fsigmoid(acc[rt][0 + ct][j] + vbi);
        const float fv = fsigmoid(acc[rt][2 + ct][j] + vbf);
        const float gv = ftanh(acc[rt][4 + ct][j] + vbg);
        const float ov = fsigmoid(acc[rt][6 + ct][j] + vbo);
        const float cn = fv * c0v + iv * gv;
        const float hn = ov * ftanh(cn);
        hout[(size_t)(s * N_ + n) * L_ + l] = f2bf(hn);
      }
    }
  }
}

// ---------------- output GEMM (verified r1/r2) ----------------
__global__ __launch_bounds__(256, 2) void out_kernel(
    const ushort_t* __restrict__ h,    // [S][N][L] bf16
    const ushort_t* __restrict__ wy,   // [S][M][L] bf16
    const float* __restrict__ by,      // [S*M]
    float* __restrict__ out)           // [N][S*M]
{
  __shared__ __align__(16) ushort_t smem[1536 * 8];
  const int tid = threadIdx.x;
  const int lane = tid & 63;
  const int w = tid >> 6;
  const int n0 = blockIdx.x * 128;
  const int m0 = blockIdx.y * 64;
  const int s = blockIdx.z;

  f32x4 acc[2][4];
  #pragma unroll
  for (int rt = 0; rt < 2; ++rt)
    #pragma unroll
    for (int ct = 0; ct < 4; ++ct) {
      f32x4 z = {0.f, 0.f, 0.f, 0.f};
      acc[rt][ct] = z;
    }

  const size_t h_row0 = (size_t)(s * N_ + n0) * L_;

  for (int t = 0; t < L_ / 64; ++t) {
    const int k0 = t * 64;
    #pragma unroll
    for (int it = 0; it < 4; ++it) {
      int chunk = it * 256 + tid;
      int r = chunk >> 3, c = chunk & 7;
      int cg = c ^ (r & 7);
      const ushort_t* src = h + h_row0 + (size_t)r * L_ + k0 + cg * 8;
      GLD16(src, &smem[(it * 256 + w * 64) * 8]);
    }
    #pragma unroll
    for (int it = 0; it < 2; ++it) {
      int chunk = it * 256 + tid;
      int rl = chunk >> 3, c = chunk & 7;
      int cg = c ^ (rl & 7);
      const ushort_t* src = wy + ((size_t)(s * M_ + m0 + rl)) * L_ + k0 + cg * 8;
      GLD16(src, &smem[(1024 + it * 256 + w * 64) * 8]);
    }
    __syncthreads();
    #pragma unroll
    for (int kk = 0; kk < 2; ++kk) {
      const int cc = kk * 4 + (lane >> 4);
      bf16x8 av[2];
      #pragma unroll
      for (int rt = 0; rt < 2; ++rt) {
        int rr = w * 32 + rt * 16 + (lane & 15);
        av[rt] = *(const bf16x8*)&smem[(rr * 8 + (cc ^ (rr & 7))) * 8];
      }
      #pragma unroll
      for (int ct = 0; ct < 4; ++ct) {
        int rl = ct * 16 + (lane & 15);
        bf16x8 b = *(const bf16x8*)&smem[(1024 + rl * 8 + (cc ^ (rl & 7))) * 8];
        acc[0][ct] = __builtin_amdgcn_mfma_f32_16x16x32_bf16(av[0], b, acc[0][ct], 0, 0, 0);
        acc[1][ct] = __builtin_amdgcn_mfma_f32_16x16x32_bf16(av[1], b, acc[1][ct], 0, 0, 0);
      }
    }
    __syncthreads();
  }

  #pragma unroll
  for (int ct = 0; ct < 4; ++ct) {
    const int m = m0 + ct * 16 + (lane & 15);
    const float vb = by[s * M_ + m];
    #pragma unroll
    for (int rt = 0; rt < 2; ++rt) {
      #pragma unroll
      for (int j = 0; j < 4; ++j) {
        const int n = n0 + w * 32 + rt * 16 + (lane >> 4) * 4 + j;
        out[(size_t)n * (S_ * M_) + s * M_ + m] = acc[rt][ct][j] + vb;
      }
    }
  }
}

// ---------------- launcher ----------------

extern "C" void kernel_launch(void* const* d_in, const int* in_sizes, int n_in,
                              void* d_out, int out_size, void* d_ws, size_t ws_size,
                              hipStream_t stream) {
  const float* mod = (const float*)d_in[0];
  const float* h0  = (const float*)d_in[1];
  const float* c0  = (const float*)d_in[2];
  const float* Wi  = (const float*)d_in[3];
  const float* bi  = (const float*)d_in[4];
  const float* Wf  = (const float*)d_in[5];
  const float* bf  = (const float*)d_in[6];
  const float* Wg  = (const float*)d_in[7];
  const float* bg  = (const float*)d_in[8];
  const float* Wo  = (const float*)d_in[9];
  const float* bo  = (const float*)d_in[10];
  const float* Wy  = (const float*)d_in[11];
  const float* by  = (const float*)d_in[12];
  float* out = (float*)d_out;

  ushort_t* ws = (ushort_t*)d_ws;
  ushort_t* xh   = ws;                                  // S*N*D bf16
  ushort_t* w4   = xh  + (size_t)S_ * N_ * D_;          // 4*S*L*D
  ushort_t* wyb  = w4  + (size_t)4 * S_ * L_ * D_;      // S*M*L
  ushort_t* hbuf = wyb + (size_t)S_ * M_ * L_;          // S*N*L

  cast5_kernel<<<dim3(512, 5), 256, 0, stream>>>(Wi, Wf, Wg, Wo, Wy, w4, wyb);
  build_xh_kernel<<<dim3(2048, 2), 256, 0, stream>>>(mod, h0, xh);
  gates_kernel<<<1024, 512, 0, stream>>>(xh, w4, bi, bf, bg, bo, c0, hbuf);
  out_kernel<<<dim3(N_ / 128, M_ / 64, S_), 256, 0, stream>>>(hbuf, wyb, by, out);
}

// Round 4
// 207.135 us; speedup vs baseline: 1.1709x; 1.1709x over previous
//
#include <hip/hip_runtime.h>
#include <stdint.h>

#define S_ 8
#define N_ 4096
#define I_ 256
#define L_ 512
#define M_ 256
#define D_ 768   // I + L
#define NT32 24  // 768/32 K-tiles

typedef __bf16 bf16x8 __attribute__((ext_vector_type(8)));
typedef float f32x4 __attribute__((ext_vector_type(4)));
typedef unsigned short ushort_t;

__device__ __forceinline__ unsigned short f2bf(float f) {
  union { float f; uint32_t u; } c; c.f = f;
  uint32_t u = c.u;
  uint32_t r = u + 0x7FFFu + ((u >> 16) & 1u);
  return (unsigned short)(r >> 16);
}

__device__ __forceinline__ float fsigmoid(float x) {
  return 1.0f / (1.0f + __expf(-x));
}
__device__ __forceinline__ float ftanh(float x) {
  float ax = fabsf(x);
  float e = __expf(-2.0f * ax);
  float t = (1.0f - e) / (1.0f + e);
  return copysignf(t, x);
}

#define GLD16(gsrc, ldst)                                                                  \
  __builtin_amdgcn_global_load_lds(                                                        \
      (const __attribute__((address_space(1))) uint32_t*)(uintptr_t)(gsrc),                \
      (__attribute__((address_space(3))) uint32_t*)(uintptr_t)(ldst), 16, 0, 0)

// ---------------- prep kernels (verified r3) ----------------

__global__ __launch_bounds__(256) void cast5_kernel(
    const float* __restrict__ Wi, const float* __restrict__ Wf,
    const float* __restrict__ Wg, const float* __restrict__ Wo,
    const float* __restrict__ Wy, ushort_t* __restrict__ w4,
    ushort_t* __restrict__ wyb) {
  const int y = blockIdx.y;
  const int GW = S_ * L_ * D_ / 4;
  const float* src;
  ushort_t* dst;
  int n4;
  if (y < 4) {
    src = (y == 0) ? Wi : (y == 1) ? Wf : (y == 2) ? Wg : Wo;
    dst = w4 + (size_t)y * S_ * L_ * D_;
    n4 = GW;
  } else {
    src = Wy; dst = wyb; n4 = S_ * M_ * L_ / 4;
  }
  int t = blockIdx.x * 256 + threadIdx.x;
  int stride = gridDim.x * 256;
  for (; t < n4; t += stride) {
    float4 v = ((const float4*)src)[t];
    ushort4 o;
    o.x = f2bf(v.x); o.y = f2bf(v.y); o.z = f2bf(v.z); o.w = f2bf(v.w);
    ((ushort4*)dst)[t] = o;
  }
}

__global__ __launch_bounds__(256) void build_xh_kernel(const float* __restrict__ mod,
                                                       const float* __restrict__ h0,
                                                       ushort_t* __restrict__ xh) {
  const int y = blockIdx.y;
  int t = blockIdx.x * 256 + threadIdx.x;
  int stride = gridDim.x * 256;
  if (y == 0) {
    const int total = S_ * N_ * (I_ / 4);
    for (; t < total; t += stride) {
      int r = t >> 6, c = t & 63;
      int s = r >> 12, n = r & (N_ - 1);
      float4 v = *(const float4*)(mod + (size_t)n * (S_ * I_) + s * I_ + c * 4);
      ushort4 o;
      o.x = f2bf(v.x); o.y = f2bf(v.y); o.z = f2bf(v.z); o.w = f2bf(v.w);
      *(ushort4*)(xh + (size_t)r * D_ + c * 4) = o;
    }
  } else {
    const int total = S_ * N_ * (L_ / 4);
    for (; t < total; t += stride) {
      int r = t >> 7, c = t & 127;
      int s = r >> 12, n = r & (N_ - 1);
      float4 v = *(const float4*)(h0 + (size_t)n * (S_ * L_) + s * L_ + c * 4);
      ushort4 o;
      o.x = f2bf(v.x); o.y = f2bf(v.y); o.z = f2bf(v.z); o.w = f2bf(v.w);
      *(ushort4*)(xh + (size_t)r * D_ + I_ + c * 4) = o;
    }
  }
}

// ---------------- gates: 256n x (4g x 64l), BK=32, double-buffered 64 KB, 1024 thr ----------------
// 16 waves (wm = w>>2 -> 64 n-rows, wl = w&3 -> 16 l-cols). Wave = 64n x (4g x 16l):
// acc[rt][cj] with cj = gate, so cell math is lane-local. 2-phase pipeline:
// STAGE(t+1) -> ds_read/MFMA(t) -> vmcnt(0) -> barrier. One drain per iter, covered by compute.
//
// LDS swizzle: BK=32 rows are 64B; pair rows into 128B super-rows and apply the
// r1-proven XOR within the 8-chunk super-row: slot' = ((r&1)*4 + c) ^ ((r>>1)&7).
// Bank slot == slot' (super-row stride 128B == bank period) -> conflict-free.

__global__ __launch_bounds__(1024, 4) void gates_kernel(
    const ushort_t* __restrict__ xh,   // [S][N][D] bf16
    const ushort_t* __restrict__ w4,   // [4][S][L][D] bf16
    const float* __restrict__ bi, const float* __restrict__ bff,
    const float* __restrict__ bg, const float* __restrict__ bo,
    const float* __restrict__ c0,      // [N][S*L] f32
    ushort_t* __restrict__ hout)       // [S][N][L] bf16
{
  // 16B slots: buf0 A [0,1024) B [1024,2048), buf1 A [2048,3072) B [3072,4096)
  __shared__ __align__(16) ushort_t smem[32768];  // 64 KB
  const int tid = threadIdx.x;
  const int lane = tid & 63;
  const int ln15 = lane & 15;
  const int ln4 = lane >> 4;          // 0..3 = k-chunk of the MFMA operand
  const int w = tid >> 6;             // 0..15
  const int wm = w >> 2;              // 0..3 -> 64 n-rows
  const int wl = w & 3;               // 0..3 -> 16 l-cols

  const int bid = blockIdx.x;
  const int s = bid & 7;              // stream-per-XCD
  const int r = bid >> 3;             // 0..127
  const int n0 = (r >> 3) << 8;       // 16 n-blocks of 256
  const int l0 = (r & 7) << 6;        // 8 l-blocks of 64

  const size_t xh_base = (size_t)(s * N_ + n0) * D_;

  // staging source decode (per thread, loop-invariant): slot = tid
  const int sr_s = tid >> 3;
  const int ch0_s = (tid & 7) ^ (sr_s & 7);
  const int rr_s = (sr_s << 1) | (ch0_s >> 2);     // row 0..255
  const int c_s = ch0_s & 3;                        // k-chunk 0..3
  const ushort_t* aSrcBase = xh + xh_base + (size_t)rr_s * D_ + (c_s << 3);
  const int gB = rr_s >> 6, llB = rr_s & 63;
  const ushort_t* bSrcBase = w4 + ((size_t)((gB * S_ + s) * L_) + l0 + llB) * D_ + (c_s << 3);
  const int ldsSlot = (w << 6) * 8;                 // wave-uniform dest (ushort units /8 -> *8 later)

  f32x4 acc[4][4];
  #pragma unroll
  for (int i = 0; i < 4; ++i)
    #pragma unroll
    for (int j = 0; j < 4; ++j) {
      f32x4 z = {0.f, 0.f, 0.f, 0.f};
      acc[i][j] = z;
    }

#define STAGE(bufA, tile) do {                                                          \
    int k0_ = (tile) << 5;                                                              \
    GLD16(aSrcBase + k0_, &smem[((bufA) + (w << 6)) * 8]);                              \
    GLD16(bSrcBase + k0_, &smem[((bufA) + 1024 + (w << 6)) * 8]);                       \
  } while (0)

  // prologue
  STAGE(0, 0);
  asm volatile("s_waitcnt vmcnt(0)" ::: "memory");
  __syncthreads();

  for (int t = 0; t < NT32; ++t) {
    const int cur = (t & 1) << 11;        // 0 or 2048
    const int nxt = cur ^ 2048;
    if (t < NT32 - 1) STAGE(nxt, t + 1);

    bf16x8 a[4];
    #pragma unroll
    for (int rt = 0; rt < 4; ++rt) {
      int rr = (wm << 6) + (rt << 4) + ln15;
      int sr = rr >> 1;
      int ch = (((rr & 1) << 2) | ln4) ^ (sr & 7);
      a[rt] = *(const bf16x8*)&smem[(cur + (sr << 3) + ch) * 8];
    }
    bf16x8 b[4];
    #pragma unroll
    for (int cj = 0; cj < 4; ++cj) {
      int rB = (cj << 6) + (wl << 4) + ln15;
      int sr = rB >> 1;
      int ch = (((rB & 1) << 2) | ln4) ^ (sr & 7);
      b[cj] = *(const bf16x8*)&smem[(cur + 1024 + (sr << 3) + ch) * 8];
    }
    #pragma unroll
    for (int rt = 0; rt < 4; ++rt)
      #pragma unroll
      for (int cj = 0; cj < 4; ++cj)
        acc[rt][cj] = __builtin_amdgcn_mfma_f32_16x16x32_bf16(a[rt], b[cj], acc[rt][cj], 0, 0, 0);

    asm volatile("s_waitcnt vmcnt(0)" ::: "memory");
    __syncthreads();
  }

  // Epilogue: D frag col = lane&15 -> l, row = (lane>>4)*4 + j -> n. cj = gate.
  const int l = l0 + (wl << 4) + ln15;
  const float vbi = bi[s * L_ + l];
  const float vbf = bff[s * L_ + l];
  const float vbg = bg[s * L_ + l];
  const float vbo = bo[s * L_ + l];
  #pragma unroll
  for (int rt = 0; rt < 4; ++rt) {
    #pragma unroll
    for (int j = 0; j < 4; ++j) {
      const int n = n0 + (wm << 6) + (rt << 4) + (ln4 << 2) + j;
      const float c0v = c0[(size_t)n * (S_ * L_) + s * L_ + l];
      const float iv = fsigmoid(acc[rt][0][j] + vbi);
      const float fv = fsigmoid(acc[rt][1][j] + vbf);
      const float gv = ftanh(acc[rt][2][j] + vbg);
      const float ov = fsigmoid(acc[rt][3][j] + vbo);
      const float cn = fv * c0v + iv * gv;
      const float hn = ov * ftanh(cn);
      hout[(size_t)(s * N_ + n) * L_ + l] = f2bf(hn);
    }
  }
#undef STAGE
}

// ---------------- output GEMM (verified r1-r3) ----------------
__global__ __launch_bounds__(256, 2) void out_kernel(
    const ushort_t* __restrict__ h,    // [S][N][L] bf16
    const ushort_t* __restrict__ wy,   // [S][M][L] bf16
    const float* __restrict__ by,      // [S*M]
    float* __restrict__ out)           // [N][S*M]
{
  __shared__ __align__(16) ushort_t smem[1536 * 8];
  const int tid = threadIdx.x;
  const int lane = tid & 63;
  const int w = tid >> 6;
  const int n0 = blockIdx.x * 128;
  const int m0 = blockIdx.y * 64;
  const int s = blockIdx.z;

  f32x4 acc[2][4];
  #pragma unroll
  for (int rt = 0; rt < 2; ++rt)
    #pragma unroll
    for (int ct = 0; ct < 4; ++ct) {
      f32x4 z = {0.f, 0.f, 0.f, 0.f};
      acc[rt][ct] = z;
    }

  const size_t h_row0 = (size_t)(s * N_ + n0) * L_;

  for (int t = 0; t < L_ / 64; ++t) {
    const int k0 = t * 64;
    #pragma unroll
    for (int it = 0; it < 4; ++it) {
      int chunk = it * 256 + tid;
      int r = chunk >> 3, c = chunk & 7;
      int cg = c ^ (r & 7);
      const ushort_t* src = h + h_row0 + (size_t)r * L_ + k0 + cg * 8;
      GLD16(src, &smem[(it * 256 + w * 64) * 8]);
    }
    #pragma unroll
    for (int it = 0; it < 2; ++it) {
      int chunk = it * 256 + tid;
      int rl = chunk >> 3, c = chunk & 7;
      int cg = c ^ (rl & 7);
      const ushort_t* src = wy + ((size_t)(s * M_ + m0 + rl)) * L_ + k0 + cg * 8;
      GLD16(src, &smem[(1024 + it * 256 + w * 64) * 8]);
    }
    __syncthreads();
    #pragma unroll
    for (int kk = 0; kk < 2; ++kk) {
      const int cc = kk * 4 + (lane >> 4);
      bf16x8 av[2];
      #pragma unroll
      for (int rt = 0; rt < 2; ++rt) {
        int rr = w * 32 + rt * 16 + (lane & 15);
        av[rt] = *(const bf16x8*)&smem[(rr * 8 + (cc ^ (rr & 7))) * 8];
      }
      #pragma unroll
      for (int ct = 0; ct < 4; ++ct) {
        int rl = ct * 16 + (lane & 15);
        bf16x8 b = *(const bf16x8*)&smem[(1024 + rl * 8 + (cc ^ (rl & 7))) * 8];
        acc[0][ct] = __builtin_amdgcn_mfma_f32_16x16x32_bf16(av[0], b, acc[0][ct], 0, 0, 0);
        acc[1][ct] = __builtin_amdgcn_mfma_f32_16x16x32_bf16(av[1], b, acc[1][ct], 0, 0, 0);
      }
    }
    __syncthreads();
  }

  #pragma unroll
  for (int ct = 0; ct < 4; ++ct) {
    const int m = m0 + ct * 16 + (lane & 15);
    const float vb = by[s * M_ + m];
    #pragma unroll
    for (int rt = 0; rt < 2; ++rt) {
      #pragma unroll
      for (int j = 0; j < 4; ++j) {
        const int n = n0 + w * 32 + rt * 16 + (lane >> 4) * 4 + j;
        out[(size_t)n * (S_ * M_) + s * M_ + m] = acc[rt][ct][j] + vb;
      }
    }
  }
}

// ---------------- launcher ----------------

extern "C" void kernel_launch(void* const* d_in, const int* in_sizes, int n_in,
                              void* d_out, int out_size, void* d_ws, size_t ws_size,
                              hipStream_t stream) {
  const float* mod = (const float*)d_in[0];
  const float* h0  = (const float*)d_in[1];
  const float* c0  = (const float*)d_in[2];
  const float* Wi  = (const float*)d_in[3];
  const float* bi  = (const float*)d_in[4];
  const float* Wf  = (const float*)d_in[5];
  const float* bf  = (const float*)d_in[6];
  const float* Wg  = (const float*)d_in[7];
  const float* bg  = (const float*)d_in[8];
  const float* Wo  = (const float*)d_in[9];
  const float* bo  = (const float*)d_in[10];
  const float* Wy  = (const float*)d_in[11];
  const float* by  = (const float*)d_in[12];
  float* out = (float*)d_out;

  ushort_t* ws = (ushort_t*)d_ws;
  ushort_t* xh   = ws;
  ushort_t* w4   = xh  + (size_t)S_ * N_ * D_;
  ushort_t* wyb  = w4  + (size_t)4 * S_ * L_ * D_;
  ushort_t* hbuf = wyb + (size_t)S_ * M_ * L_;

  cast5_kernel<<<dim3(512, 5), 256, 0, stream>>>(Wi, Wf, Wg, Wo, Wy, w4, wyb);
  build_xh_kernel<<<dim3(2048, 2), 256, 0, stream>>>(mod, h0, xh);
  gates_kernel<<<1024, 1024, 0, stream>>>(xh, w4, bi, bf, bg, bo, c0, hbuf);
  out_kernel<<<dim3(N_ / 128, M_ / 64, S_), 256, 0, stream>>>(hbuf, wyb, by, out);
}